// Round 10
// baseline (1060.871 us; speedup 1.0000x reference)
//
#include <hip/hip_runtime.h>

#pragma clang fp contract(off)

#define HH 256
#define WW 256
#define NVERTS 6890
#define NFACES 13776
#define RASTN (NFACES + 1)          // +1 sentinel record (depth=BIG, never wins)
#define LISTSTRIDE 13824            // multiple of 64, >= NFACES
#define RCHUNK 64                   // faces per work item (one wave)
#define MAXCH 216                   // LISTSTRIDE / RCHUNK
#define SLABS 2                     // bin units per tile
#define WSUB 1728                   // faces per wave in bin (27 x 64)
#define NITER 27
#define SLABSZ (4 * WSUB)           // 6912 faces per unit
#define NBLKM 1024                  // mega blocks: 4/CU x 256 CU, guaranteed resident
#define BIGF 1000000000.0f
#define EPSF 1e-8f

// c(i) = ((i+0.5)/256)*2 - 1  -- exact in f32, matches reference pixel coords
__device__ __forceinline__ float pixc(int i) {
    return __fsub_rn(__fmul_rn(__fdiv_rn(__fadd_rn((float)i, 0.5f), 256.0f), 2.0f), 1.0f);
}

// order-preserving float->uint (all finite values, negatives included)
__device__ __forceinline__ unsigned int fsort(float f) {
    unsigned int u = __float_as_uint(f);
    return (u & 0x80000000u) ? ~u : (u | 0x80000000u);
}

// Grid barrier: arrive (release) + spin (acquire), device scope. Safe because
// NBLKM=1024 blocks x 256 thr = 4 blocks/CU x 256 CUs, VGPR<=128 (launch
// bounds) and LDS 27.6KB <= 40KB/block -> ALL blocks co-resident by
// construction.
__device__ __forceinline__ void gsync(int* bar, int nblk) {
    __syncthreads();
    if (threadIdx.x == 0) {
        __threadfence();
        __hip_atomic_fetch_add(bar, 1, __ATOMIC_RELEASE, __HIP_MEMORY_SCOPE_AGENT);
        while (__hip_atomic_load(bar, __ATOMIC_ACQUIRE, __HIP_MEMORY_SCOPE_AGENT) < nblk)
            __builtin_amdgcn_s_sleep(2);
        __threadfence();
    }
    __syncthreads();
}

// 64-B face record layout (floats):
// [0]=x2 [1]=y2 [2]=A [3]=B [4]=C [5]=D [6]=inv [7]=fid [8]=z0 [9]=z1 [10]=z2
// Degenerate / sentinel: A=B=C=D=0, inv=1 -> w0=w1=0,w2=1, depth = exactly BIG
// -> never wins strict-<, identical to ref's inside &= |denom|>=EPS.

__device__ __forceinline__ void d_precompute(
    int idx, const float* __restrict__ src_cam, const float* __restrict__ src_verts,
    const float* __restrict__ tgt_cam, const float* __restrict__ tgt_verts,
    const int* __restrict__ faces,
    float4* __restrict__ rast64, float4* __restrict__ bbox,
    float4* __restrict__ flowg, unsigned long long* __restrict__ zbuf, int B)
{
    if (idx < B * HH * WW) zbuf[idx] = ~0ull;   // background sentinel
    if (idx >= B * RASTN) return;
    int b = idx / RASTN;
    int f = idx - b * RASTN;
    float4* rr = rast64 + ((size_t)b * RASTN + f) * 4;
    if (f == NFACES) {   // sentinel record
        rr[0] = make_float4(0.0f, 0.0f, 0.0f, 0.0f);
        rr[1] = make_float4(0.0f, 0.0f, 1.0f, __int_as_float(-1));
        rr[2] = make_float4(BIGF, BIGF, BIGF, 0.0f);
        rr[3] = make_float4(0.0f, 0.0f, 0.0f, 0.0f);
        return;
    }
    int i0 = faces[3*f+0], i1 = faces[3*f+1], i2 = faces[3*f+2];

    float tc0 = tgt_cam[3*b+0], tc1 = tgt_cam[3*b+1], tc2 = tgt_cam[3*b+2];
    const float* tv = tgt_verts + (size_t)b * NVERTS * 3;
    float x0 = __fmul_rn(tc0, __fadd_rn(tv[3*i0+0], tc1));
    float y0 = -__fmul_rn(tc0, __fadd_rn(tv[3*i0+1], tc2));
    float z0 = tv[3*i0+2];
    float x1 = __fmul_rn(tc0, __fadd_rn(tv[3*i1+0], tc1));
    float y1 = -__fmul_rn(tc0, __fadd_rn(tv[3*i1+1], tc2));
    float z1 = tv[3*i1+2];
    float x2 = __fmul_rn(tc0, __fadd_rn(tv[3*i2+0], tc1));
    float y2 = -__fmul_rn(tc0, __fadd_rn(tv[3*i2+1], tc2));
    float z2 = tv[3*i2+2];

    float A  = __fsub_rn(y1, y2);
    float D  = __fsub_rn(x0, x2);
    float Bc = __fsub_rn(x2, x1);
    float E_ = __fsub_rn(y0, y2);
    float denom = __fadd_rn(__fmul_rn(A, D), __fmul_rn(Bc, E_));
    bool valid = (fabsf(denom) >= EPSF);
    float inv = __fdiv_rn(1.0f, valid ? denom : 1.0f);
    float Cc = __fsub_rn(y2, y0);

    if (valid) {
        rr[0] = make_float4(x2, y2, A, Bc);
        rr[1] = make_float4(Cc, D, inv, __int_as_float(f));
        rr[2] = make_float4(z0, z1, z2, 0.0f);
    } else {
        rr[0] = make_float4(0.0f, 0.0f, 0.0f, 0.0f);
        rr[1] = make_float4(0.0f, 0.0f, 1.0f, __int_as_float(f));
        rr[2] = make_float4(BIGF, BIGF, BIGF, 0.0f);
    }
    rr[3] = make_float4(0.0f, 0.0f, 0.0f, 0.0f);

    // conservative bbox: vertex bbox + slop + sliver extension (see R8 note)
    if (bbox) {
        float4 bb;
        if (valid) {
            float xmn = fminf(fminf(x0, x1), x2), xmx = fmaxf(fmaxf(x0, x1), x2);
            float ymn = fminf(fminf(y0, y1), y2), ymx = fmaxf(fmaxf(y0, y1), y2);
            float S = fmaxf(fmaxf(fabsf(xmn), fabsf(xmx)),
                            fmaxf(fabsf(ymn), fabsf(ymx))) + 1.01f;
            float slop = 2e-6f * S;
            float l0 = sqrtf(D*D + E_*E_);
            float dx1v = x1 - x2, dy1v = y1 - y2;
            float l1 = sqrtf(dx1v*dx1v + dy1v*dy1v);
            float dx2v = x1 - x0, dy2v = y1 - y0;
            float l2 = sqrtf(dx2v*dx2v + dy2v*dy2v);
            float mp = fmaxf(fmaxf(l0*l1, l1*l2), l0*l2);
            float Ex = slop * mp / fabsf(denom);
            float m = Ex + slop + 1e-4f;
            bb = make_float4(xmn - m, ymn - m, xmx + m, ymx + m);
        } else {
            bb = make_float4(2e9f, 2e9f, -2e9f, -2e9f);   // empty
        }
        bbox[(size_t)b * NFACES + f] = bb;
    }

    float sc0 = src_cam[3*b+0], sc1 = src_cam[3*b+1], sc2 = src_cam[3*b+2];
    const float* sv = src_verts + (size_t)b * NVERTS * 3;
    float g0x = __fmul_rn(sc0, __fadd_rn(sv[3*i0+0], sc1));
    float g0y = __fmul_rn(sc0, __fadd_rn(sv[3*i0+1], sc2));
    float g1x = __fmul_rn(sc0, __fadd_rn(sv[3*i1+0], sc1));
    float g1y = __fmul_rn(sc0, __fadd_rn(sv[3*i1+1], sc2));
    float g2x = __fmul_rn(sc0, __fadd_rn(sv[3*i2+0], sc1));
    float g2y = __fmul_rn(sc0, __fadd_rn(sv[3*i2+1], sc2));
    size_t fo = ((size_t)b * NFACES + f) * 2;
    flowg[fo+0] = make_float4(g0x, g0y, g1x, g1y);
    flowg[fo+1] = make_float4(g2x, g2y, 0.0f, 0.0f);
}

// One (tileG, 64-face chunk) raster work item, executed by one wave.
// NO LDS: indices via uniform int4 (scalar pipe), records via uniform 64-B
// s_loads. Each lane owns 4 pixels sharing one column (dx/Adx/Cdx computed
// once per face, bit-identical reuse). u64 atomicMin of (sortable_depth,fid)
// == exact lexicographic (depth, face index) min == reference semantics.
__device__ __forceinline__ void d_raster_entry(
    int tileG, int k, const float* __restrict__ rast64,
    const int* __restrict__ lp, unsigned long long* __restrict__ zbuf, int lane)
{
    int b = tileG >> 8, tile = tileG & 255;
    const float* rb = rast64 + (size_t)b * RASTN * 16;
    int tX = tile & 15, tY = tile >> 4;
    int col = lane & 15, row0 = lane >> 4;
    int pxi = tX * 16 + col;
    float px = pixc(pxi);
    float py0 = pixc(tY * 16 + row0);
    float py1 = pixc(tY * 16 + row0 + 4);
    float py2 = pixc(tY * 16 + row0 + 8);
    float py3 = pixc(tY * 16 + row0 + 12);

    float z0c = BIGF, z1c = BIGF, z2c = BIGF, z3c = BIGF;
    int f0c = -1, f1c = -1, f2c = -1, f3c = -1;

    for (int j = 0; j < RCHUNK; j += 4) {
        int4 fis;
        if (lp) {
            fis = *(const int4*)(lp + j);
        } else {
            int base = k * RCHUNK + j;
            fis.x = min(base + 0, NFACES); fis.y = min(base + 1, NFACES);
            fis.z = min(base + 2, NFACES); fis.w = min(base + 3, NFACES);
        }
        #pragma unroll
        for (int q = 0; q < 4; ++q) {
            int fi = (q == 0) ? fis.x : (q == 1) ? fis.y : (q == 2) ? fis.z : fis.w;
            fi = __builtin_amdgcn_readfirstlane(fi);
            const float* r = rb + (size_t)fi * 16;
            float X2 = r[0], Y2 = r[1], A = r[2], Bc = r[3];
            float Cc = r[4], Dd = r[5], inv = r[6];
            int   fid = __float_as_int(r[7]);
            float Z0 = r[8], Z1 = r[9], Z2 = r[10];

            float dx  = __fsub_rn(px, X2);
            float Adx = __fmul_rn(A, dx);
            float Cdx = __fmul_rn(Cc, dx);
            auto evalp = [&](float py, float& zc, int& fc) {
                float dy = __fsub_rn(py, Y2);
                float w0 = __fmul_rn(__fadd_rn(Adx, __fmul_rn(Bc, dy)), inv);
                float w1 = __fmul_rn(__fadd_rn(Cdx, __fmul_rn(Dd, dy)), inv);
                float w2 = __fsub_rn(__fsub_rn(1.0f, w0), w1);
                float d  = __fadd_rn(__fadd_rn(__fmul_rn(w0, Z0), __fmul_rn(w1, Z1)),
                                     __fmul_rn(w2, Z2));
                float mm = fminf(fminf(w0, w1), w2);    // v_min3
                bool ins = (mm >= 0.0f) & (d < zc);
                if (ins) { zc = d; fc = fid; }
            };
            evalp(py0, z0c, f0c);
            evalp(py1, z1c, f1c);
            evalp(py2, z2c, f2c);
            evalp(py3, z3c, f3c);
        }
    }

    auto commit = [&](int rowk, float zc, int fc) {
        if (fc >= 0) {
            unsigned long long pk =
                ((unsigned long long)fsort(zc) << 32) | (unsigned int)fc;
            int pyi = tY * 16 + row0 + rowk * 4;
            atomicMin(&zbuf[((size_t)b << 16) | (pyi << 8) | pxi], pk);
        }
    };
    commit(0, z0c, f0c);
    commit(1, z1c, f1c);
    commit(2, z2c, f2c);
    commit(3, z3c, f3c);
}

// Per-pixel resolve: read winning fid, recompute w0,w1 from the record
// (same _rn sequence -> bit-identical), flow gather, bilinear grid sample.
__device__ __forceinline__ void d_resolve(
    int idx, const float* __restrict__ rast64, const float4* __restrict__ flowg,
    const unsigned long long* __restrict__ zbuf,
    const float* __restrict__ src_img, float* __restrict__ out, int B)
{
    int b = idx >> 16;
    int pix = idx & 65535;
    int pxi = pix & 255, pyi = pix >> 8;
    float px = pixc(pxi), py = pixc(pyi);

    unsigned int fid = (unsigned int)zbuf[idx];
    float fx, fy;
    if (fid != 0xFFFFFFFFu) {
        const float* r = rast64 + ((size_t)b * RASTN + fid) * 16;
        float dx = __fsub_rn(px, r[0]);
        float dy = __fsub_rn(py, r[1]);
        float w0 = __fmul_rn(__fadd_rn(__fmul_rn(r[2], dx), __fmul_rn(r[3], dy)), r[6]);
        float w1 = __fmul_rn(__fadd_rn(__fmul_rn(r[4], dx), __fmul_rn(r[5], dy)), r[6]);
        float w2 = __fsub_rn(__fsub_rn(1.0f, w0), w1);
        const float4* fg = flowg + ((size_t)b * NFACES + fid) * 2;
        float4 g0 = fg[0];
        float4 g1 = fg[1];
        fx = __fadd_rn(__fadd_rn(__fmul_rn(w0, g0.x), __fmul_rn(w1, g0.z)),
                       __fmul_rn(w2, g1.x));
        fy = __fadd_rn(__fadd_rn(__fmul_rn(w0, g0.y), __fmul_rn(w1, g0.w)),
                       __fmul_rn(w2, g1.y));
    } else {
        fx = -2.0f; fy = -2.0f;
    }

    float ix = __fmul_rn(__fsub_rn(__fmul_rn(__fadd_rn(fx, 1.0f), 256.0f), 1.0f), 0.5f);
    float iy = __fmul_rn(__fsub_rn(__fmul_rn(__fadd_rn(fy, 1.0f), 256.0f), 1.0f), 0.5f);
    ix = fminf(fmaxf(ix, 0.0f), 255.0f);
    iy = fminf(fmaxf(iy, 0.0f), 255.0f);
    float x0f = floorf(ix), y0f = floorf(iy);
    float wx = __fsub_rn(ix, x0f), wy = __fsub_rn(iy, y0f);
    int x0i = (int)x0f, y0i = (int)y0f;
    int x1i = min(x0i + 1, 255), y1i = min(y0i + 1, 255);
    float omwx = __fsub_rn(1.0f, wx), omwy = __fsub_rn(1.0f, wy);
    float wa = __fmul_rn(omwx, omwy);
    float wb = __fmul_rn(wx, omwy);
    float wc = __fmul_rn(omwx, wy);
    float wd = __fmul_rn(wx, wy);
    const float* img = src_img + (size_t)b * 3 * HH * WW;
    int o00 = y0i * WW + x0i, o01 = y0i * WW + x1i;
    int o10 = y1i * WW + x0i, o11 = y1i * WW + x1i;
    float* ob = out + (size_t)b * 3 * HH * WW + (size_t)pyi * WW + pxi;
    for (int c = 0; c < 3; ++c) {
        const float* ic = img + (size_t)c * HH * WW;
        float Ia = ic[o00], Ib = ic[o01], Ic = ic[o10], Id = ic[o11];
        float val = __fadd_rn(__fadd_rn(__fadd_rn(__fmul_rn(Ia, wa), __fmul_rn(Ib, wb)),
                                        __fmul_rn(Ic, wc)),
                              __fmul_rn(Id, wd));
        ob[(size_t)c * HH * WW] = val;
    }
}

// ---------------------------------------------------------------------------
// init: zero barriers/head/qcount/counts/done (re-poisoned to 0xAA between
// timed launches -> must be re-zeroed every call).
// ---------------------------------------------------------------------------
__global__ __launch_bounds__(256) void init_kernel(int* __restrict__ ctrl,
                                                   int* __restrict__ counts,
                                                   int* __restrict__ done, int B)
{
    int t = threadIdx.x;
    if (t < 8) ctrl[t] = 0;
    for (int i = t; i < B * 256; i += 256) { counts[i] = 0; done[i] = 0; }
}

// ---------------------------------------------------------------------------
// MEGA kernel: 4 phases with grid barriers.
//  A: precompute records/bbox/flow + zbuf init
//  B: bin (per-wave LDS compaction, 1 global atomic per wave, last slab of
//     each tile pads list to x64 and enqueues (tileG,chunk) items)
//  C: raster via work-stealing pop on a global head pointer (near-perfect
//     balance; drain tail = one 64-face chunk)
//  D: resolve (flow + grid sample)
// ctrl: [0..2]=barriers, [4]=head, [5]=qcount
// ---------------------------------------------------------------------------
__global__ __launch_bounds__(256, 4) void mega_kernel(
    const float* __restrict__ src_cam, const float* __restrict__ src_verts,
    const float* __restrict__ tgt_cam, const float* __restrict__ tgt_verts,
    const int* __restrict__ faces, const float* __restrict__ src_img,
    float4* __restrict__ rast64, float4* __restrict__ bbox,
    float4* __restrict__ flowg, unsigned long long* __restrict__ zbuf,
    int* __restrict__ ctrl, int* __restrict__ counts, int* __restrict__ done,
    unsigned int* __restrict__ queue, int* __restrict__ lists,
    float* __restrict__ out, int B)
{
    __shared__ int seg[4][WSUB];
    int t = threadIdx.x;
    int wv = t >> 6, lane = t & 63;
    int nblk = gridDim.x;
    int gsz = nblk * 256;
    int* bar = ctrl;
    int* head = ctrl + 4;
    int* qcount = ctrl + 5;

    // ---- Phase A: precompute ----
    int nMaxA = B * HH * WW; if (B * RASTN > nMaxA) nMaxA = B * RASTN;
    for (int idx = blockIdx.x * 256 + t; idx < nMaxA; idx += gsz)
        d_precompute(idx, src_cam, src_verts, tgt_cam, tgt_verts, faces,
                     rast64, bbox, flowg, zbuf, B);
    gsync(&bar[0], nblk);

    // ---- Phase B: bin ----
    int nUnits = B * 256 * SLABS;
    for (int u = blockIdx.x; u < nUnits; u += nblk) {
        int b = u / (256 * SLABS);
        int r = u - b * 256 * SLABS;
        int slab = r >> 8;
        int tile = r & 255;
        int tileG = b * 256 + tile;
        int tX = tile & 15, tY = tile >> 4;
        float txmin = pixc(tX * 16), txmax = pixc(tX * 16 + 15);
        float tymin = pixc(tY * 16), tymax = pixc(tY * 16 + 15);
        const float4* bbs = bbox + (size_t)b * NFACES;
        int* mylist = lists + (size_t)tileG * LISTSTRIDE;
        int wlo = slab * SLABSZ + wv * WSUB;
        int cnt = 0;
        #pragma unroll
        for (int it = 0; it < NITER; ++it) {
            int f = wlo + it * 64 + lane;
            bool pass = false;
            if (f < NFACES) {
                float4 bb = bbs[f];
                pass = (bb.x <= txmax) & (bb.z >= txmin) &
                       (bb.y <= tymax) & (bb.w >= tymin);
            }
            unsigned long long m = __ballot(pass);
            if (pass) {
                int pre = __popcll(m & ((1ull << lane) - 1ull));
                seg[wv][cnt + pre] = f;
            }
            cnt += __popcll(m);
        }
        int gbase = 0;
        if (lane == 0 && cnt) gbase = atomicAdd(&counts[tileG], cnt);
        gbase = __shfl(gbase, 0);
        for (int i = lane; i < cnt; i += 64) mylist[gbase + i] = seg[wv][i];

        __syncthreads();
        if (t == 0) {
            __threadfence();
            if (atomicAdd(&done[tileG], 1) == SLABS - 1) {
                int c = atomicAdd(&counts[tileG], 0);   // coherent read
                int padded = (c + RCHUNK - 1) & ~(RCHUNK - 1);
                for (int i = c; i < padded; ++i) mylist[i] = NFACES;
                int nch = padded / RCHUNK;
                if (nch) {
                    int qb = atomicAdd(qcount, nch);
                    for (int kk = 0; kk < nch; ++kk)
                        queue[qb + kk] = ((unsigned int)tileG << 8) | (unsigned int)kk;
                }
            }
        }
        __syncthreads();
    }
    gsync(&bar[1], nblk);

    // ---- Phase C: raster, work-stealing ----
    int qn = __hip_atomic_load(qcount, __ATOMIC_ACQUIRE, __HIP_MEMORY_SCOPE_AGENT);
    qn = __builtin_amdgcn_readfirstlane(qn);
    for (;;) {
        int e = 0;
        if (lane == 0) e = atomicAdd(head, 1);
        e = __shfl(e, 0);
        if (e >= qn) break;
        unsigned int ent = queue[e];
        int tileG = (int)(ent >> 8);
        int k = (int)(ent & 255u);
        tileG = __builtin_amdgcn_readfirstlane(tileG);
        k = __builtin_amdgcn_readfirstlane(k);
        const int* lp = lists + (size_t)tileG * LISTSTRIDE + k * RCHUNK;
        d_raster_entry(tileG, k, (const float*)rast64, lp, zbuf, lane);
    }
    gsync(&bar[2], nblk);

    // ---- Phase D: resolve ----
    int nPix = B * HH * WW;
    for (int idx = blockIdx.x * 256 + t; idx < nPix; idx += gsz)
        d_resolve(idx, (const float*)rast64, flowg, zbuf, src_img, out, B);
}

// ---------------------------------------------------------------------------
// Fallback path (workspace too small for lists): 3 plain kernels, full scan.
// ---------------------------------------------------------------------------
__global__ __launch_bounds__(256) void k_pre(
    const float* __restrict__ src_cam, const float* __restrict__ src_verts,
    const float* __restrict__ tgt_cam, const float* __restrict__ tgt_verts,
    const int* __restrict__ faces, float4* __restrict__ rast64,
    float4* __restrict__ flowg, unsigned long long* __restrict__ zbuf, int B)
{
    int idx = blockIdx.x * 256 + threadIdx.x;
    d_precompute(idx, src_cam, src_verts, tgt_cam, tgt_verts, faces,
                 rast64, nullptr, flowg, zbuf, B);
}

__global__ __launch_bounds__(256) void k_raster_all(
    const float* __restrict__ rast64, unsigned long long* __restrict__ zbuf, int B)
{
    int wv = threadIdx.x >> 6, lane = threadIdx.x & 63;
    int waveId = blockIdx.x * 4 + wv;
    int nw = gridDim.x * 4;
    int total = B * 256 * MAXCH;
    for (int e = waveId; e < total; e += nw) {
        int tileG = e / MAXCH, k = e - tileG * MAXCH;
        d_raster_entry(tileG, k, rast64, nullptr, zbuf, lane);
    }
}

__global__ __launch_bounds__(256) void k_resolve(
    const float* __restrict__ rast64, const float4* __restrict__ flowg,
    const unsigned long long* __restrict__ zbuf,
    const float* __restrict__ src_img, float* __restrict__ out, int B)
{
    int idx = blockIdx.x * 256 + threadIdx.x;
    if (idx < B * HH * WW)
        d_resolve(idx, rast64, flowg, zbuf, src_img, out, B);
}

extern "C" void kernel_launch(void* const* d_in, const int* in_sizes, int n_in,
                              void* d_out, int out_size, void* d_ws, size_t ws_size,
                              hipStream_t stream)
{
    const float* src_img   = (const float*)d_in[0];
    const float* src_cam   = (const float*)d_in[1];
    const float* src_verts = (const float*)d_in[2];
    const float* tgt_cam   = (const float*)d_in[3];
    const float* tgt_verts = (const float*)d_in[4];
    const int*   faces     = (const int*)d_in[5];
    int B = in_sizes[1] / 3;   // src_cam is [B,3]

    size_t off = 0;
    auto alloc = [&](size_t bytes) {
        size_t o = off;
        off = (off + bytes + 255) & ~(size_t)255;
        return o;
    };
    size_t rastOff = alloc((size_t)B * RASTN * 64);
    size_t flowOff = alloc((size_t)B * NFACES * 2 * sizeof(float4));
    size_t zbufOff = alloc((size_t)B * HH * WW * sizeof(unsigned long long));
    size_t bbOff   = alloc((size_t)B * NFACES * sizeof(float4));
    size_t ctlOff  = alloc(8 * sizeof(int));
    size_t cntOff  = alloc((size_t)B * 256 * sizeof(int));
    size_t donOff  = alloc((size_t)B * 256 * sizeof(int));
    size_t quOff   = alloc((size_t)B * 256 * MAXCH * sizeof(unsigned int));
    size_t listOff = alloc((size_t)B * 256 * LISTSTRIDE * sizeof(int));
    bool binned = (off <= ws_size) && (B == 2);   // mega residency math sized for B=2

    char* ws = (char*)d_ws;
    float4* rast64 = (float4*)(ws + rastOff);
    float4* flowg  = (float4*)(ws + flowOff);
    unsigned long long* zbuf = (unsigned long long*)(ws + zbufOff);

    if (binned) {
        float4* bbox  = (float4*)(ws + bbOff);
        int* ctrl     = (int*)(ws + ctlOff);
        int* counts   = (int*)(ws + cntOff);
        int* done     = (int*)(ws + donOff);
        unsigned int* queue = (unsigned int*)(ws + quOff);
        int* lists    = (int*)(ws + listOff);

        init_kernel<<<1, 256, 0, stream>>>(ctrl, counts, done, B);
        mega_kernel<<<NBLKM, 256, 0, stream>>>(
            src_cam, src_verts, tgt_cam, tgt_verts, faces, src_img,
            rast64, bbox, flowg, zbuf, ctrl, counts, done, queue, lists,
            (float*)d_out, B);
    } else {
        int nMaxA = B * HH * WW; if (B * RASTN > nMaxA) nMaxA = B * RASTN;
        k_pre<<<(nMaxA + 255) / 256, 256, 0, stream>>>(
            src_cam, src_verts, tgt_cam, tgt_verts, faces, rast64, flowg, zbuf, B);
        k_raster_all<<<NBLKM, 256, 0, stream>>>((const float*)rast64, zbuf, B);
        k_resolve<<<(B * HH * WW + 255) / 256, 256, 0, stream>>>(
            (const float*)rast64, flowg, zbuf, src_img, (float*)d_out, B);
    }
}

// Round 11
// 254.058 us; speedup vs baseline: 4.1757x; 4.1757x over previous
//
#include <hip/hip_runtime.h>

#pragma clang fp contract(off)

#define HH 256
#define WW 256
#define NVERTS 6890
#define NFACES 13776
#define RASTN (NFACES + 1)          // +1 sentinel record (depth=BIG, never wins)
#define LISTSTRIDE 13824            // multiple of 128, >= NFACES
#define RCHUNK 128                  // faces per work item (one wave)
#define MAXCH 108                   // LISTSTRIDE / RCHUNK
#define SLABS 4                     // bin blocks per tile
#define WSUB 896                    // faces per wave (14 x 64)
#define NITER 14
#define SLABSZ (4 * WSUB)           // 3584 faces per block
#define NBLK 1024                   // raster blocks (x4 waves)
#define NWAVES (NBLK * 4)
#define SEEDMOD 8                   // seed pass covers chunks k % 8 == 0
#define BIGF 1000000000.0f
#define EPSF 1e-8f

// c(i) = ((i+0.5)/256)*2 - 1  -- exact in f32, matches reference pixel coords
__device__ __forceinline__ float pixc(int i) {
    return __fsub_rn(__fmul_rn(__fdiv_rn(__fadd_rn((float)i, 0.5f), 256.0f), 2.0f), 1.0f);
}

// order-preserving float->uint (all finite values, negatives included)
__device__ __forceinline__ unsigned int fsort(float f) {
    unsigned int u = __float_as_uint(f);
    return (u & 0x80000000u) ? ~u : (u | 0x80000000u);
}

// 64-B face record layout (floats):
// [0]=x2 [1]=y2 [2]=A [3]=B [4]=C [5]=D [6]=inv [7]=fid [8]=z0 [9]=z1 [10]=z2
// [11]=minz_key (sortable u32 of min(z)-slop, for conservative early-z skip)
// Degenerate / sentinel: A=B=C=D=0, inv=1 -> w0=w1=0,w2=1, depth = exactly BIG
// -> never wins strict-<, identical to ref's inside &= |denom|>=EPS.

// ---------------------------------------------------------------------------
// Kernel 1: precompute 64-B records + conservative bbox + flow verts; zbuf
// init; control zero-init (ws re-poisoned 0xAA before every timed launch).
// bbox = vertex bbox + slop + sliver extension (conservative, see R8 note).
// minz_key: slop = 1e-5*(max|z|+1) >= 10x the worst rn-chain dip of the
// interpolated depth below min(z0,z1,z2) -> skip is provably conservative.
// ---------------------------------------------------------------------------
__global__ __launch_bounds__(256) void precompute_kernel(
    const float* __restrict__ src_cam, const float* __restrict__ src_verts,
    const float* __restrict__ tgt_cam, const float* __restrict__ tgt_verts,
    const int* __restrict__ faces,
    float4* __restrict__ rast64, float4* __restrict__ bbox,
    float4* __restrict__ flowg,
    unsigned long long* __restrict__ zbuf,
    int* __restrict__ counts, int* __restrict__ done, int* __restrict__ qcount,
    int B)
{
    int idx = blockIdx.x * blockDim.x + threadIdx.x;
    if (idx < B * HH * WW) zbuf[idx] = ~0ull;   // background sentinel
    if (counts && idx < B * 256) { counts[idx] = 0; done[idx] = 0; }
    if (qcount && idx == 0) qcount[0] = 0;
    if (idx >= B * RASTN) return;
    int b = idx / RASTN;
    int f = idx - b * RASTN;
    float4* rr = rast64 + ((size_t)b * RASTN + f) * 4;
    if (f == NFACES) {   // sentinel record
        float zslop = 1e-5f * (BIGF + 1.0f);
        rr[0] = make_float4(0.0f, 0.0f, 0.0f, 0.0f);
        rr[1] = make_float4(0.0f, 0.0f, 1.0f, __int_as_float(-1));
        rr[2] = make_float4(BIGF, BIGF, BIGF, __uint_as_float(fsort(BIGF - zslop)));
        rr[3] = make_float4(0.0f, 0.0f, 0.0f, 0.0f);
        return;
    }
    int i0 = faces[3*f+0], i1 = faces[3*f+1], i2 = faces[3*f+2];

    float tc0 = tgt_cam[3*b+0], tc1 = tgt_cam[3*b+1], tc2 = tgt_cam[3*b+2];
    const float* tv = tgt_verts + (size_t)b * NVERTS * 3;
    float x0 = __fmul_rn(tc0, __fadd_rn(tv[3*i0+0], tc1));
    float y0 = -__fmul_rn(tc0, __fadd_rn(tv[3*i0+1], tc2));
    float z0 = tv[3*i0+2];
    float x1 = __fmul_rn(tc0, __fadd_rn(tv[3*i1+0], tc1));
    float y1 = -__fmul_rn(tc0, __fadd_rn(tv[3*i1+1], tc2));
    float z1 = tv[3*i1+2];
    float x2 = __fmul_rn(tc0, __fadd_rn(tv[3*i2+0], tc1));
    float y2 = -__fmul_rn(tc0, __fadd_rn(tv[3*i2+1], tc2));
    float z2 = tv[3*i2+2];

    float A  = __fsub_rn(y1, y2);
    float D  = __fsub_rn(x0, x2);
    float Bc = __fsub_rn(x2, x1);
    float E_ = __fsub_rn(y0, y2);
    float denom = __fadd_rn(__fmul_rn(A, D), __fmul_rn(Bc, E_));
    bool valid = (fabsf(denom) >= EPSF);
    float inv = __fdiv_rn(1.0f, valid ? denom : 1.0f);
    float Cc = __fsub_rn(y2, y0);

    // conservative early-z key
    float zmax3 = fmaxf(fabsf(z0), fmaxf(fabsf(z1), fabsf(z2)));
    float mz = valid ? fminf(z0, fminf(z1, z2)) : BIGF;
    float zslop = 1e-5f * ((valid ? zmax3 : BIGF) + 1.0f);
    unsigned int zkey = fsort(mz - zslop);

    if (valid) {
        rr[0] = make_float4(x2, y2, A, Bc);
        rr[1] = make_float4(Cc, D, inv, __int_as_float(f));
        rr[2] = make_float4(z0, z1, z2, __uint_as_float(zkey));
    } else {
        rr[0] = make_float4(0.0f, 0.0f, 0.0f, 0.0f);
        rr[1] = make_float4(0.0f, 0.0f, 1.0f, __int_as_float(f));
        rr[2] = make_float4(BIGF, BIGF, BIGF, __uint_as_float(zkey));
    }
    rr[3] = make_float4(0.0f, 0.0f, 0.0f, 0.0f);

    if (bbox) {
        float4 bb;
        if (valid) {
            float xmn = fminf(fminf(x0, x1), x2), xmx = fmaxf(fmaxf(x0, x1), x2);
            float ymn = fminf(fminf(y0, y1), y2), ymx = fmaxf(fmaxf(y0, y1), y2);
            float S = fmaxf(fmaxf(fabsf(xmn), fabsf(xmx)),
                            fmaxf(fabsf(ymn), fabsf(ymx))) + 1.01f;
            float slop = 2e-6f * S;
            float l0 = sqrtf(D*D + E_*E_);
            float dx1v = x1 - x2, dy1v = y1 - y2;
            float l1 = sqrtf(dx1v*dx1v + dy1v*dy1v);
            float dx2v = x1 - x0, dy2v = y1 - y0;
            float l2 = sqrtf(dx2v*dx2v + dy2v*dy2v);
            float mp = fmaxf(fmaxf(l0*l1, l1*l2), l0*l2);
            float Ex = slop * mp / fabsf(denom);
            float m = Ex + slop + 1e-4f;
            bb = make_float4(xmn - m, ymn - m, xmx + m, ymx + m);
        } else {
            bb = make_float4(2e9f, 2e9f, -2e9f, -2e9f);   // empty
        }
        bbox[(size_t)b * NFACES + f] = bb;
    }

    float sc0 = src_cam[3*b+0], sc1 = src_cam[3*b+1], sc2 = src_cam[3*b+2];
    const float* sv = src_verts + (size_t)b * NVERTS * 3;
    float g0x = __fmul_rn(sc0, __fadd_rn(sv[3*i0+0], sc1));
    float g0y = __fmul_rn(sc0, __fadd_rn(sv[3*i0+1], sc2));
    float g1x = __fmul_rn(sc0, __fadd_rn(sv[3*i1+0], sc1));
    float g1y = __fmul_rn(sc0, __fadd_rn(sv[3*i1+1], sc2));
    float g2x = __fmul_rn(sc0, __fadd_rn(sv[3*i2+0], sc1));
    float g2y = __fmul_rn(sc0, __fadd_rn(sv[3*i2+1], sc2));
    size_t fo = ((size_t)b * NFACES + f) * 2;
    flowg[fo+0] = make_float4(g0x, g0y, g1x, g1y);
    flowg[fo+1] = make_float4(g2x, g2y, 0.0f, 0.0f);
}

// ---------------------------------------------------------------------------
// Kernel 2: bin (unchanged from R9, the 204us config). Per-wave LDS-buffered
// compaction, one global atomicAdd per wave, coalesced segment dump.
// Order-independent (raster merge is an atomicMin). Last slab pads to x128
// with the sentinel face and enqueues (tileG,chunk) items.
// ---------------------------------------------------------------------------
__global__ __launch_bounds__(256) void bin_kernel(
    const float4* __restrict__ bbox, int* __restrict__ lists,
    int* __restrict__ counts, int* __restrict__ done,
    unsigned int* __restrict__ queue, int* __restrict__ qcount, int B)
{
    __shared__ int seg[4][WSUB];
    int tile = blockIdx.x;          // 0..255
    int slab = blockIdx.y;
    int b = blockIdx.z;
    int tileG = b * 256 + tile;
    int tX = tile & 15, tY = tile >> 4;
    float txmin = pixc(tX * 16), txmax = pixc(tX * 16 + 15);
    float tymin = pixc(tY * 16), tymax = pixc(tY * 16 + 15);

    int wv = threadIdx.x >> 6, lane = threadIdx.x & 63;
    const float4* bbs = bbox + (size_t)b * NFACES;
    int* mylist = lists + (size_t)tileG * LISTSTRIDE;
    int wlo = slab * SLABSZ + wv * WSUB;
    int cnt = 0;

    #pragma unroll
    for (int it = 0; it < NITER; ++it) {
        int f = wlo + it * 64 + lane;
        bool pass = false;
        if (f < NFACES) {
            float4 bb = bbs[f];
            pass = (bb.x <= txmax) & (bb.z >= txmin) &
                   (bb.y <= tymax) & (bb.w >= tymin);
        }
        unsigned long long m = __ballot(pass);
        if (pass) {
            int pre = __popcll(m & ((1ull << lane) - 1ull));
            seg[wv][cnt + pre] = f;
        }
        cnt += __popcll(m);
    }

    int gbase = 0;
    if (lane == 0 && cnt) gbase = atomicAdd(&counts[tileG], cnt);
    gbase = __shfl(gbase, 0);
    for (int i = lane; i < cnt; i += 64) mylist[gbase + i] = seg[wv][i];

    __syncthreads();
    if (threadIdx.x == 0) {
        __threadfence();
        if (atomicAdd(&done[tileG], 1) == SLABS - 1) {
            int c = atomicAdd(&counts[tileG], 0);     // coherent read
            int padded = (c + RCHUNK - 1) & ~(RCHUNK - 1);
            for (int i = c; i < padded; ++i) mylist[i] = NFACES;
            int nch = padded >> 7;
            if (nch) {
                int qb = atomicAdd(qcount, nch);
                for (int kk = 0; kk < nch; ++kk)
                    queue[qb + kk] = ((unsigned int)tileG << 8) | (unsigned int)kk;
            }
        }
    }
}

// ---------------------------------------------------------------------------
// Kernel 3: raster. mode 0 = SEED (chunks k%8==0, no early-z): converges the
// zbuf with ~17% of faces. mode 1 = MAIN (remaining chunks, early-z): per
// chunk, read the 256 pixels' current sortable-z high dwords (4 loads/lane +
// 6-step butterfly max -> scalar smax); per face one uniform scalar compare
// of the precomputed minz_key vs smax skips provably-losing faces (~3 cyc
// vs ~72). Skip is conservative: minz_key > smax => d > z_p strictly for
// every pixel => can't win even on the fid tie-break. Seed chunks are
// excluded in main (their commits are already in zbuf). mode 2 = fallback
// (all chunks, no lists, no early-z). NO LDS; indices via uniform int4,
// records via uniform 64-B s_loads; 4 px/lane sharing one column. u64
// atomicMin of (sortable_depth,fid) == exact lexicographic min ==
// reference's first-argmin + strict-< semantics. All depth math _rn.
// ---------------------------------------------------------------------------
__global__ __launch_bounds__(256) void raster_kernel(
    const float* __restrict__ rast64, const int* __restrict__ lists,
    const unsigned int* __restrict__ queue, const int* __restrict__ qcount,
    unsigned long long* __restrict__ zbuf, int B, int mode)
{
    int wv = threadIdx.x >> 6, lane = threadIdx.x & 63;
    int waveId = blockIdx.x * 4 + wv;
    int qn = queue ? qcount[0] : B * 256 * MAXCH;
    qn = __builtin_amdgcn_readfirstlane(qn);

    for (int e = waveId; e < qn; e += NWAVES) {
        int tileG, k;
        if (queue) {
            unsigned int ent = queue[e];
            tileG = (int)(ent >> 8); k = (int)(ent & 255u);
        } else {
            tileG = e / MAXCH; k = e - tileG * MAXCH;
        }
        tileG = __builtin_amdgcn_readfirstlane(tileG);
        k = __builtin_amdgcn_readfirstlane(k);
        int km = k & (SEEDMOD - 1);
        if (mode == 0 && km != 0) continue;
        if (mode == 1 && km == 0) continue;

        int b = tileG >> 8, tile = tileG & 255;
        const int* lp = lists ? (lists + (size_t)tileG * LISTSTRIDE + k * RCHUNK)
                              : nullptr;
        const float* rb = rast64 + (size_t)b * RASTN * 16;

        int tX = tile & 15, tY = tile >> 4;
        int col = lane & 15, row0 = lane >> 4;
        int pxi = tX * 16 + col;
        float px = pixc(pxi);
        float py0 = pixc(tY * 16 + row0);
        float py1 = pixc(tY * 16 + row0 + 4);
        float py2 = pixc(tY * 16 + row0 + 8);
        float py3 = pixc(tY * 16 + row0 + 12);
        size_t pixbase = ((size_t)b << 16) | ((size_t)(tY * 16 + row0) << 8) | pxi;

        unsigned int smax = 0xFFFFFFFFu;
        if (mode == 1) {
            // current zbuf sortable-depth (high dword) for my 4 pixels
            unsigned int m0 = *((const unsigned int*)(zbuf + pixbase) + 1);
            unsigned int m1 = *((const unsigned int*)(zbuf + pixbase + 4*256) + 1);
            unsigned int m2 = *((const unsigned int*)(zbuf + pixbase + 8*256) + 1);
            unsigned int m3 = *((const unsigned int*)(zbuf + pixbase + 12*256) + 1);
            unsigned int m = m0 > m1 ? m0 : m1;
            unsigned int n = m2 > m3 ? m2 : m3;
            m = m > n ? m : n;
            #pragma unroll
            for (int off = 32; off >= 1; off >>= 1) {
                unsigned int o = (unsigned int)__shfl_xor((int)m, off);
                m = m > o ? m : o;
            }
            smax = __builtin_amdgcn_readfirstlane(m);
        }

        float z0c = BIGF, z1c = BIGF, z2c = BIGF, z3c = BIGF;
        int f0c = -1, f1c = -1, f2c = -1, f3c = -1;

        for (int j = 0; j < RCHUNK; j += 4) {
            int4 fis;
            if (lp) {
                fis = *(const int4*)(lp + j);
            } else {
                int base = k * RCHUNK + j;
                fis.x = min(base + 0, NFACES); fis.y = min(base + 1, NFACES);
                fis.z = min(base + 2, NFACES); fis.w = min(base + 3, NFACES);
            }
            #pragma unroll
            for (int q = 0; q < 4; ++q) {
                int fi = (q == 0) ? fis.x : (q == 1) ? fis.y : (q == 2) ? fis.z : fis.w;
                fi = __builtin_amdgcn_readfirstlane(fi);
                const float* r = rb + (size_t)fi * 16;
                if (mode == 1) {
                    unsigned int zkey = __builtin_amdgcn_readfirstlane(
                        ((const unsigned int*)r)[11]);
                    if (zkey > smax) continue;    // provably can't win anywhere
                }
                float X2 = r[0], Y2 = r[1], A = r[2], Bc = r[3];
                float Cc = r[4], Dd = r[5], inv = r[6];
                int   fid = __float_as_int(r[7]);
                float Z0 = r[8], Z1 = r[9], Z2 = r[10];

                float dx  = __fsub_rn(px, X2);
                float Adx = __fmul_rn(A, dx);
                float Cdx = __fmul_rn(Cc, dx);
                auto evalp = [&](float py, float& zc, int& fc) {
                    float dy = __fsub_rn(py, Y2);
                    float w0 = __fmul_rn(__fadd_rn(Adx, __fmul_rn(Bc, dy)), inv);
                    float w1 = __fmul_rn(__fadd_rn(Cdx, __fmul_rn(Dd, dy)), inv);
                    float w2 = __fsub_rn(__fsub_rn(1.0f, w0), w1);
                    float d  = __fadd_rn(__fadd_rn(__fmul_rn(w0, Z0), __fmul_rn(w1, Z1)),
                                         __fmul_rn(w2, Z2));
                    float mm = fminf(fminf(w0, w1), w2);    // v_min3
                    bool ins = (mm >= 0.0f) & (d < zc);
                    if (ins) { zc = d; fc = fid; }
                };
                evalp(py0, z0c, f0c);
                evalp(py1, z1c, f1c);
                evalp(py2, z2c, f2c);
                evalp(py3, z3c, f3c);
            }
        }

        auto commit = [&](int rowk, float zc, int fc) {
            if (fc >= 0) {
                unsigned long long pk =
                    ((unsigned long long)fsort(zc) << 32) | (unsigned int)fc;
                atomicMin(&zbuf[pixbase + (size_t)rowk * 4 * 256], pk);
            }
        };
        commit(0, z0c, f0c);
        commit(1, z1c, f1c);
        commit(2, z2c, f2c);
        commit(3, z3c, f3c);
    }
}

// ---------------------------------------------------------------------------
// Kernel 4: resolve. Per pixel: read winning fid, recompute w0,w1 from the
// record (same _rn sequence -> bit-identical), flow gather, bilinear sample.
// ---------------------------------------------------------------------------
__global__ __launch_bounds__(256) void resolve_kernel(
    const float* __restrict__ rast64, const float4* __restrict__ flowg,
    const unsigned long long* __restrict__ zbuf,
    const float* __restrict__ src_img, float* __restrict__ out, int B)
{
    int idx = blockIdx.x * 256 + threadIdx.x;
    if (idx >= B * HH * WW) return;
    int b = idx >> 16;
    int pix = idx & 65535;
    int pxi = pix & 255, pyi = pix >> 8;
    float px = pixc(pxi), py = pixc(pyi);

    unsigned int fid = (unsigned int)zbuf[idx];
    float fx, fy;
    if (fid != 0xFFFFFFFFu) {
        const float* r = rast64 + ((size_t)b * RASTN + fid) * 16;
        float dx = __fsub_rn(px, r[0]);
        float dy = __fsub_rn(py, r[1]);
        float w0 = __fmul_rn(__fadd_rn(__fmul_rn(r[2], dx), __fmul_rn(r[3], dy)), r[6]);
        float w1 = __fmul_rn(__fadd_rn(__fmul_rn(r[4], dx), __fmul_rn(r[5], dy)), r[6]);
        float w2 = __fsub_rn(__fsub_rn(1.0f, w0), w1);
        const float4* fg = flowg + ((size_t)b * NFACES + fid) * 2;
        float4 g0 = fg[0];
        float4 g1 = fg[1];
        fx = __fadd_rn(__fadd_rn(__fmul_rn(w0, g0.x), __fmul_rn(w1, g0.z)),
                       __fmul_rn(w2, g1.x));
        fy = __fadd_rn(__fadd_rn(__fmul_rn(w0, g0.y), __fmul_rn(w1, g0.w)),
                       __fmul_rn(w2, g1.y));
    } else {
        fx = -2.0f; fy = -2.0f;
    }

    float ix = __fmul_rn(__fsub_rn(__fmul_rn(__fadd_rn(fx, 1.0f), 256.0f), 1.0f), 0.5f);
    float iy = __fmul_rn(__fsub_rn(__fmul_rn(__fadd_rn(fy, 1.0f), 256.0f), 1.0f), 0.5f);
    ix = fminf(fmaxf(ix, 0.0f), 255.0f);
    iy = fminf(fmaxf(iy, 0.0f), 255.0f);
    float x0f = floorf(ix), y0f = floorf(iy);
    float wx = __fsub_rn(ix, x0f), wy = __fsub_rn(iy, y0f);
    int x0i = (int)x0f, y0i = (int)y0f;
    int x1i = min(x0i + 1, 255), y1i = min(y0i + 1, 255);
    float omwx = __fsub_rn(1.0f, wx), omwy = __fsub_rn(1.0f, wy);
    float wa = __fmul_rn(omwx, omwy);
    float wb = __fmul_rn(wx, omwy);
    float wc = __fmul_rn(omwx, wy);
    float wd = __fmul_rn(wx, wy);
    const float* img = src_img + (size_t)b * 3 * HH * WW;
    int o00 = y0i * WW + x0i, o01 = y0i * WW + x1i;
    int o10 = y1i * WW + x0i, o11 = y1i * WW + x1i;
    float* ob = out + (size_t)b * 3 * HH * WW + (size_t)pyi * WW + pxi;
    for (int c = 0; c < 3; ++c) {
        const float* ic = img + (size_t)c * HH * WW;
        float Ia = ic[o00], Ib = ic[o01], Ic = ic[o10], Id = ic[o11];
        float val = __fadd_rn(__fadd_rn(__fadd_rn(__fmul_rn(Ia, wa), __fmul_rn(Ib, wb)),
                                        __fmul_rn(Ic, wc)),
                              __fmul_rn(Id, wd));
        ob[(size_t)c * HH * WW] = val;
    }
}

extern "C" void kernel_launch(void* const* d_in, const int* in_sizes, int n_in,
                              void* d_out, int out_size, void* d_ws, size_t ws_size,
                              hipStream_t stream)
{
    const float* src_img   = (const float*)d_in[0];
    const float* src_cam   = (const float*)d_in[1];
    const float* src_verts = (const float*)d_in[2];
    const float* tgt_cam   = (const float*)d_in[3];
    const float* tgt_verts = (const float*)d_in[4];
    const int*   faces     = (const int*)d_in[5];
    int B = in_sizes[1] / 3;   // src_cam is [B,3]

    size_t off = 0;
    auto alloc = [&](size_t bytes) {
        size_t o = off;
        off = (off + bytes + 255) & ~(size_t)255;
        return o;
    };
    size_t rastOff = alloc((size_t)B * RASTN * 64);
    size_t bbOff   = alloc((size_t)B * NFACES * sizeof(float4));
    size_t flowOff = alloc((size_t)B * NFACES * 2 * sizeof(float4));
    size_t zbufOff = alloc((size_t)B * HH * WW * sizeof(unsigned long long));
    size_t cntOff  = alloc((size_t)B * 256 * sizeof(int));
    size_t donOff  = alloc((size_t)B * 256 * sizeof(int));
    size_t qcOff   = alloc(sizeof(int));
    size_t quOff   = alloc((size_t)B * 256 * MAXCH * sizeof(unsigned int));
    size_t listOff = alloc((size_t)B * 256 * LISTSTRIDE * sizeof(int));
    bool binned = (off <= ws_size);

    char* ws = (char*)d_ws;
    float4* rast64 = (float4*)(ws + rastOff);
    float4* bbox   = binned ? (float4*)(ws + bbOff) : nullptr;
    float4* flowg  = (float4*)(ws + flowOff);
    unsigned long long* zbuf = (unsigned long long*)(ws + zbufOff);
    int* counts = binned ? (int*)(ws + cntOff) : nullptr;
    int* done   = binned ? (int*)(ws + donOff) : nullptr;
    int* qcount = binned ? (int*)(ws + qcOff)  : nullptr;
    unsigned int* queue = binned ? (unsigned int*)(ws + quOff) : nullptr;
    int* lists  = binned ? (int*)(ws + listOff) : nullptr;

    int nInit = B * HH * WW;
    int nPre  = B * RASTN;
    int nMax  = nInit > nPre ? nInit : nPre;
    precompute_kernel<<<(nMax + 255) / 256, 256, 0, stream>>>(
        src_cam, src_verts, tgt_cam, tgt_verts, faces,
        rast64, bbox, flowg, zbuf, counts, done, qcount, B);
    if (binned) {
        bin_kernel<<<dim3(256, SLABS, B), 256, 0, stream>>>(
            bbox, lists, counts, done, queue, qcount, B);
        // seed pass: chunks k%8==0, no early-z
        raster_kernel<<<NBLK, 256, 0, stream>>>(
            (const float*)rast64, lists, queue, qcount, zbuf, B, 0);
        // main pass: remaining chunks with conservative early-z skip
        raster_kernel<<<NBLK, 256, 0, stream>>>(
            (const float*)rast64, lists, queue, qcount, zbuf, B, 1);
    } else {
        raster_kernel<<<NBLK, 256, 0, stream>>>(
            (const float*)rast64, nullptr, nullptr, nullptr, zbuf, B, 2);
    }
    resolve_kernel<<<(B * HH * WW + 255) / 256, 256, 0, stream>>>(
        (const float*)rast64, flowg, zbuf, src_img, (float*)d_out, B);
}

// Round 12
// 223.772 us; speedup vs baseline: 4.7408x; 1.1353x over previous
//
#include <hip/hip_runtime.h>

#pragma clang fp contract(off)

#define HH 256
#define WW 256
#define NVERTS 6890
#define NFACES 13776
#define RASTN (NFACES + 1)          // +1 sentinel record (depth=BIG, never wins)
#define LISTSTRIDE 13824            // multiple of 128, >= NFACES
#define RCHUNK 128                  // faces per work item (one wave)
#define MAXCH 108                   // LISTSTRIDE / RCHUNK
#define SLABS 4                     // bin blocks per tile
#define WSUB 896                    // faces per wave (14 x 64)
#define NITER 14
#define SLABSZ (4 * WSUB)           // 3584 faces per block
#define NBLK 1024                   // raster blocks (x4 waves)
#define NWAVES (NBLK * 4)
#define BIGF 1000000000.0f
#define EPSF 1e-8f

// c(i) = ((i+0.5)/256)*2 - 1  -- exact in f32, matches reference pixel coords
__device__ __forceinline__ float pixc(int i) {
    return __fsub_rn(__fmul_rn(__fdiv_rn(__fadd_rn((float)i, 0.5f), 256.0f), 2.0f), 1.0f);
}

// order-preserving float->uint (all finite values, negatives included)
__device__ __forceinline__ unsigned int fsort(float f) {
    unsigned int u = __float_as_uint(f);
    return (u & 0x80000000u) ? ~u : (u | 0x80000000u);
}

// 64-B face record layout (floats):
// [0]=x2 [1]=y2 [2]=A [3]=B [4]=C [5]=D [6]=inv [7]=fid [8]=z0 [9]=z1 [10]=z2
// Degenerate / sentinel: A=B=C=D=0, inv=1 -> w0=w1=0,w2=1, depth = exactly BIG
// -> never wins strict-<, identical to ref's inside &= |denom|>=EPS.

// Evaluate one face (uniform record pointer) against a lane's 4 pixels
// (one column, rows r,r+4,r+8,r+12). All _rn, no FMA contraction ->
// bit-identical to the f32 reference. dx/Adx/Cdx shared across the 4 px.
__device__ __forceinline__ void eval4(
    const float* __restrict__ r, float px, const float* py,
    float* zc, int* fc)
{
    float X2 = r[0], Y2 = r[1], A = r[2], Bc = r[3];
    float Cc = r[4], Dd = r[5], inv = r[6];
    int   fid = __float_as_int(r[7]);
    float Z0 = r[8], Z1 = r[9], Z2 = r[10];
    float dx  = __fsub_rn(px, X2);
    float Adx = __fmul_rn(A, dx);
    float Cdx = __fmul_rn(Cc, dx);
    #pragma unroll
    for (int p = 0; p < 4; ++p) {
        float dy = __fsub_rn(py[p], Y2);
        float w0 = __fmul_rn(__fadd_rn(Adx, __fmul_rn(Bc, dy)), inv);
        float w1 = __fmul_rn(__fadd_rn(Cdx, __fmul_rn(Dd, dy)), inv);
        float w2 = __fsub_rn(__fsub_rn(1.0f, w0), w1);
        float d  = __fadd_rn(__fadd_rn(__fmul_rn(w0, Z0), __fmul_rn(w1, Z1)),
                             __fmul_rn(w2, Z2));
        float mm = fminf(fminf(w0, w1), w2);    // v_min3
        bool ins = (mm >= 0.0f) & (d < zc[p]);
        if (ins) { zc[p] = d; fc[p] = fid; }
    }
}

// ---------------------------------------------------------------------------
// Kernel 1: precompute 64-B records + conservative bbox + dense zkeys + flow
// verts; zbuf init; control zero-init.
// bbox = vertex bbox + slop + sliver extension (conservative; R8 derivation).
// zkey = fsort(min(z) - zslop), zslop = 1e-5*(max|z|+1) >= 10x the worst
// rn-chain dip of interpolated depth below min(z) -> early-z skip provable.
// ---------------------------------------------------------------------------
__global__ __launch_bounds__(256) void precompute_kernel(
    const float* __restrict__ src_cam, const float* __restrict__ src_verts,
    const float* __restrict__ tgt_cam, const float* __restrict__ tgt_verts,
    const int* __restrict__ faces,
    float4* __restrict__ rast64, float4* __restrict__ bbox,
    unsigned int* __restrict__ zkeys, float4* __restrict__ flowg,
    unsigned long long* __restrict__ zbuf,
    int* __restrict__ counts, int* __restrict__ done, int* __restrict__ qcount,
    int B)
{
    int idx = blockIdx.x * blockDim.x + threadIdx.x;
    if (idx < B * HH * WW) zbuf[idx] = ~0ull;   // background sentinel
    if (counts && idx < B * 256) { counts[idx] = 0; done[idx] = 0; }
    if (qcount && idx == 0) qcount[0] = 0;
    if (idx >= B * RASTN) return;
    int b = idx / RASTN;
    int f = idx - b * RASTN;
    float4* rr = rast64 + ((size_t)b * RASTN + f) * 4;
    if (f == NFACES) {   // sentinel record
        rr[0] = make_float4(0.0f, 0.0f, 0.0f, 0.0f);
        rr[1] = make_float4(0.0f, 0.0f, 1.0f, __int_as_float(-1));
        rr[2] = make_float4(BIGF, BIGF, BIGF, 0.0f);
        rr[3] = make_float4(0.0f, 0.0f, 0.0f, 0.0f);
        if (zkeys) zkeys[(size_t)b * RASTN + f] = fsort(BIGF - 1e-5f * (BIGF + 1.0f));
        return;
    }
    int i0 = faces[3*f+0], i1 = faces[3*f+1], i2 = faces[3*f+2];

    float tc0 = tgt_cam[3*b+0], tc1 = tgt_cam[3*b+1], tc2 = tgt_cam[3*b+2];
    const float* tv = tgt_verts + (size_t)b * NVERTS * 3;
    float x0 = __fmul_rn(tc0, __fadd_rn(tv[3*i0+0], tc1));
    float y0 = -__fmul_rn(tc0, __fadd_rn(tv[3*i0+1], tc2));
    float z0 = tv[3*i0+2];
    float x1 = __fmul_rn(tc0, __fadd_rn(tv[3*i1+0], tc1));
    float y1 = -__fmul_rn(tc0, __fadd_rn(tv[3*i1+1], tc2));
    float z1 = tv[3*i1+2];
    float x2 = __fmul_rn(tc0, __fadd_rn(tv[3*i2+0], tc1));
    float y2 = -__fmul_rn(tc0, __fadd_rn(tv[3*i2+1], tc2));
    float z2 = tv[3*i2+2];

    float A  = __fsub_rn(y1, y2);
    float D  = __fsub_rn(x0, x2);
    float Bc = __fsub_rn(x2, x1);
    float E_ = __fsub_rn(y0, y2);
    float denom = __fadd_rn(__fmul_rn(A, D), __fmul_rn(Bc, E_));
    bool valid = (fabsf(denom) >= EPSF);
    float inv = __fdiv_rn(1.0f, valid ? denom : 1.0f);
    float Cc = __fsub_rn(y2, y0);

    if (valid) {
        rr[0] = make_float4(x2, y2, A, Bc);
        rr[1] = make_float4(Cc, D, inv, __int_as_float(f));
        rr[2] = make_float4(z0, z1, z2, 0.0f);
    } else {
        rr[0] = make_float4(0.0f, 0.0f, 0.0f, 0.0f);
        rr[1] = make_float4(0.0f, 0.0f, 1.0f, __int_as_float(f));
        rr[2] = make_float4(BIGF, BIGF, BIGF, 0.0f);
    }
    rr[3] = make_float4(0.0f, 0.0f, 0.0f, 0.0f);

    if (zkeys) {
        float zmax3 = fmaxf(fabsf(z0), fmaxf(fabsf(z1), fabsf(z2)));
        float mz = valid ? fminf(z0, fminf(z1, z2)) : BIGF;
        float zslop = 1e-5f * ((valid ? zmax3 : BIGF) + 1.0f);
        zkeys[(size_t)b * RASTN + f] = fsort(mz - zslop);
    }

    if (bbox) {
        float4 bb;
        if (valid) {
            float xmn = fminf(fminf(x0, x1), x2), xmx = fmaxf(fmaxf(x0, x1), x2);
            float ymn = fminf(fminf(y0, y1), y2), ymx = fmaxf(fmaxf(y0, y1), y2);
            float S = fmaxf(fmaxf(fabsf(xmn), fabsf(xmx)),
                            fmaxf(fabsf(ymn), fabsf(ymx))) + 1.01f;
            float slop = 2e-6f * S;
            float l0 = sqrtf(D*D + E_*E_);
            float dx1v = x1 - x2, dy1v = y1 - y2;
            float l1 = sqrtf(dx1v*dx1v + dy1v*dy1v);
            float dx2v = x1 - x0, dy2v = y1 - y0;
            float l2 = sqrtf(dx2v*dx2v + dy2v*dy2v);
            float mp = fmaxf(fmaxf(l0*l1, l1*l2), l0*l2);
            float Ex = slop * mp / fabsf(denom);
            float m = Ex + slop + 1e-4f;
            bb = make_float4(xmn - m, ymn - m, xmx + m, ymx + m);
        } else {
            bb = make_float4(2e9f, 2e9f, -2e9f, -2e9f);   // empty
        }
        bbox[(size_t)b * NFACES + f] = bb;
    }

    float sc0 = src_cam[3*b+0], sc1 = src_cam[3*b+1], sc2 = src_cam[3*b+2];
    const float* sv = src_verts + (size_t)b * NVERTS * 3;
    float g0x = __fmul_rn(sc0, __fadd_rn(sv[3*i0+0], sc1));
    float g0y = __fmul_rn(sc0, __fadd_rn(sv[3*i0+1], sc2));
    float g1x = __fmul_rn(sc0, __fadd_rn(sv[3*i1+0], sc1));
    float g1y = __fmul_rn(sc0, __fadd_rn(sv[3*i1+1], sc2));
    float g2x = __fmul_rn(sc0, __fadd_rn(sv[3*i2+0], sc1));
    float g2y = __fmul_rn(sc0, __fadd_rn(sv[3*i2+1], sc2));
    size_t fo = ((size_t)b * NFACES + f) * 2;
    flowg[fo+0] = make_float4(g0x, g0y, g1x, g1y);
    flowg[fo+1] = make_float4(g2x, g2y, 0.0f, 0.0f);
}

// ---------------------------------------------------------------------------
// Kernel 2: bin + static seed. Cull loop = R9's (per-wave LDS compaction,
// one global atomicAdd per wave, coalesced dump). The LAST finishing slab
// block per tile additionally:
//  - pads the list to x128 with the sentinel face and enqueues (tileG,chunk);
//  - SEEDS the zbuf with faces 0..255 (read directly from rast64 -- no
//    cross-block list reads, so no XCD-coherence hazard), committing via the
//    usual u64 atomicMin (idempotent with later re-evaluation);
//  - computes tileSmax[tileG] = max over the tile's 256 px of the post-seed
//    winning sortable-depth (0xFFFFFFFF if any pixel unseeded), via LDS
//    atomicMin + butterfly reduce. Main raster uses it for early-z.
// ---------------------------------------------------------------------------
__global__ __launch_bounds__(256) void bin_kernel(
    const float4* __restrict__ bbox, const float* __restrict__ rast64,
    int* __restrict__ lists, int* __restrict__ counts, int* __restrict__ done,
    unsigned int* __restrict__ queue, int* __restrict__ qcount,
    unsigned int* __restrict__ tileSmax, unsigned long long* __restrict__ zbuf,
    int B)
{
    __shared__ int seg[4][WSUB];
    __shared__ unsigned int sz[256];
    __shared__ unsigned int wmax[4];
    __shared__ int isLast;
    int tile = blockIdx.x;          // 0..255
    int slab = blockIdx.y;
    int b = blockIdx.z;
    int tileG = b * 256 + tile;
    int tX = tile & 15, tY = tile >> 4;
    float txmin = pixc(tX * 16), txmax = pixc(tX * 16 + 15);
    float tymin = pixc(tY * 16), tymax = pixc(tY * 16 + 15);

    int wv = threadIdx.x >> 6, lane = threadIdx.x & 63;
    const float4* bbs = bbox + (size_t)b * NFACES;
    int* mylist = lists + (size_t)tileG * LISTSTRIDE;
    int wlo = slab * SLABSZ + wv * WSUB;
    int cnt = 0;

    #pragma unroll
    for (int it = 0; it < NITER; ++it) {
        int f = wlo + it * 64 + lane;
        bool pass = false;
        if (f < NFACES) {
            float4 bb = bbs[f];
            pass = (bb.x <= txmax) & (bb.z >= txmin) &
                   (bb.y <= tymax) & (bb.w >= tymin);
        }
        unsigned long long m = __ballot(pass);
        if (pass) {
            int pre = __popcll(m & ((1ull << lane) - 1ull));
            seg[wv][cnt + pre] = f;
        }
        cnt += __popcll(m);
    }

    int gbase = 0;
    if (lane == 0 && cnt) gbase = atomicAdd(&counts[tileG], cnt);
    gbase = __shfl(gbase, 0);
    for (int i = lane; i < cnt; i += 64) mylist[gbase + i] = seg[wv][i];

    __syncthreads();
    if (threadIdx.x == 0) {
        isLast = 0;
        __threadfence();
        if (atomicAdd(&done[tileG], 1) == SLABS - 1) {
            int c = atomicAdd(&counts[tileG], 0);     // coherent read
            int padded = (c + RCHUNK - 1) & ~(RCHUNK - 1);
            for (int i = c; i < padded; ++i) mylist[i] = NFACES;
            int nch = padded >> 7;
            if (nch) {
                int qb = atomicAdd(qcount, nch);
                for (int kk = 0; kk < nch; ++kk)
                    queue[qb + kk] = ((unsigned int)tileG << 8) | (unsigned int)kk;
            }
            isLast = 1;
        }
    }
    __syncthreads();

    if (isLast) {
        sz[threadIdx.x] = 0xFFFFFFFFu;
        __syncthreads();
        const float* rb = rast64 + (size_t)b * RASTN * 16;
        int col = lane & 15, row0 = lane >> 4;
        int pxi = tX * 16 + col;
        float px = pixc(pxi);
        float py[4] = { pixc(tY*16 + row0),     pixc(tY*16 + row0 + 4),
                        pixc(tY*16 + row0 + 8), pixc(tY*16 + row0 + 12) };
        float zc[4] = { BIGF, BIGF, BIGF, BIGF };
        int   fc[4] = { -1, -1, -1, -1 };
        int fbase = wv * 64;                      // waves cover faces 0..255
        for (int j = 0; j < 64; j += 4) {
            eval4(rb + (size_t)(fbase + j + 0) * 16, px, py, zc, fc);
            eval4(rb + (size_t)(fbase + j + 1) * 16, px, py, zc, fc);
            eval4(rb + (size_t)(fbase + j + 2) * 16, px, py, zc, fc);
            eval4(rb + (size_t)(fbase + j + 3) * 16, px, py, zc, fc);
        }
        #pragma unroll
        for (int p = 0; p < 4; ++p) {
            if (fc[p] >= 0) {
                unsigned int key = fsort(zc[p]);
                unsigned long long pk = ((unsigned long long)key << 32) |
                                        (unsigned int)fc[p];
                int pyi = tY * 16 + row0 + p * 4;
                atomicMin(&zbuf[((size_t)b << 16) | (pyi << 8) | pxi], pk);
                atomicMin(&sz[(row0 + p * 4) * 16 + col], key);
            }
        }
        __syncthreads();
        unsigned int v = sz[threadIdx.x];
        #pragma unroll
        for (int off = 32; off >= 1; off >>= 1) {
            unsigned int o = (unsigned int)__shfl_xor((int)v, off);
            v = v > o ? v : o;
        }
        if (lane == 0) wmax[wv] = v;
        __syncthreads();
        if (threadIdx.x == 0) {
            unsigned int m01 = wmax[0] > wmax[1] ? wmax[0] : wmax[1];
            unsigned int m23 = wmax[2] > wmax[3] ? wmax[2] : wmax[3];
            tileSmax[tileG] = m01 > m23 ? m01 : m23;
        }
    }
}

// ---------------------------------------------------------------------------
// Kernel 3: raster with vectorized early-z. Per (tileG,chunk) entry:
//  - one scalar load of tileSmax (conservative upper bound on all 256 px
//    winners; stale reads only ever LARGER -> still conservative);
//  - 2 coalesced index loads + 2 vector zkey gathers per lane (pipelined,
//    replaces R11's 128 serial scalar load-branch chain);
//  - ballot-compact survivors to per-wave LDS, pad to x4 with sentinel,
//    then the proven 4-wide uniform-record eval on survivors only.
// u64 atomicMin of (sortable_depth,fid) == exact lexicographic min ==
// reference's first-argmin + strict-< semantics.
// ---------------------------------------------------------------------------
__global__ __launch_bounds__(256) void raster_kernel(
    const float* __restrict__ rast64, const unsigned int* __restrict__ zkeys,
    const int* __restrict__ lists, const unsigned int* __restrict__ queue,
    const int* __restrict__ qcount, const unsigned int* __restrict__ tileSmax,
    unsigned long long* __restrict__ zbuf, int B)
{
    __shared__ int seg[4][RCHUNK];
    int wv = threadIdx.x >> 6, lane = threadIdx.x & 63;
    int waveId = blockIdx.x * 4 + wv;
    int qn = queue ? qcount[0] : B * 256 * MAXCH;
    qn = __builtin_amdgcn_readfirstlane(qn);

    for (int e = waveId; e < qn; e += NWAVES) {
        int tileG, k;
        if (queue) {
            unsigned int ent = queue[e];
            tileG = (int)(ent >> 8); k = (int)(ent & 255u);
        } else {
            tileG = e / MAXCH; k = e - tileG * MAXCH;
        }
        tileG = __builtin_amdgcn_readfirstlane(tileG);
        k = __builtin_amdgcn_readfirstlane(k);
        int b = tileG >> 8, tile = tileG & 255;
        const float* rb = rast64 + (size_t)b * RASTN * 16;

        int tX = tile & 15, tY = tile >> 4;
        int col = lane & 15, row0 = lane >> 4;
        int pxi = tX * 16 + col;
        float px = pixc(pxi);
        float py[4] = { pixc(tY*16 + row0),     pixc(tY*16 + row0 + 4),
                        pixc(tY*16 + row0 + 8), pixc(tY*16 + row0 + 12) };
        size_t pixbase = ((size_t)b << 16) | ((size_t)(tY*16 + row0) << 8) | pxi;

        float zc[4] = { BIGF, BIGF, BIGF, BIGF };
        int   fc[4] = { -1, -1, -1, -1 };

        if (lists) {
            const int* lp = lists + (size_t)tileG * LISTSTRIDE + k * RCHUNK;
            unsigned int smax = tileSmax[tileG];
            smax = (unsigned int)__builtin_amdgcn_readfirstlane((int)smax);
            const unsigned int* zk = zkeys + (size_t)b * RASTN;
            int fiA = lp[lane], fiB = lp[64 + lane];
            unsigned int zkA = zk[fiA], zkB = zk[fiB];
            bool pA = (zkA <= smax), pB = (zkB <= smax);
            unsigned long long mA = __ballot(pA);
            int cnt = __popcll(mA);
            if (pA) seg[wv][__popcll(mA & ((1ull << lane) - 1ull))] = fiA;
            unsigned long long mB = __ballot(pB);
            if (pB) seg[wv][cnt + __popcll(mB & ((1ull << lane) - 1ull))] = fiB;
            cnt += __popcll(mB);
            int cnt4 = (cnt + 3) & ~3;
            if (lane < cnt4 - cnt) seg[wv][cnt + lane] = NFACES;
            for (int j = 0; j < cnt4; j += 4) {
                int f0 = __builtin_amdgcn_readfirstlane(seg[wv][j+0]);
                int f1 = __builtin_amdgcn_readfirstlane(seg[wv][j+1]);
                int f2 = __builtin_amdgcn_readfirstlane(seg[wv][j+2]);
                int f3 = __builtin_amdgcn_readfirstlane(seg[wv][j+3]);
                eval4(rb + (size_t)f0 * 16, px, py, zc, fc);
                eval4(rb + (size_t)f1 * 16, px, py, zc, fc);
                eval4(rb + (size_t)f2 * 16, px, py, zc, fc);
                eval4(rb + (size_t)f3 * 16, px, py, zc, fc);
            }
        } else {
            int base = k * RCHUNK;
            for (int j = 0; j < RCHUNK; j += 4) {
                eval4(rb + (size_t)min(base+j+0, NFACES) * 16, px, py, zc, fc);
                eval4(rb + (size_t)min(base+j+1, NFACES) * 16, px, py, zc, fc);
                eval4(rb + (size_t)min(base+j+2, NFACES) * 16, px, py, zc, fc);
                eval4(rb + (size_t)min(base+j+3, NFACES) * 16, px, py, zc, fc);
            }
        }

        #pragma unroll
        for (int p = 0; p < 4; ++p) {
            if (fc[p] >= 0) {
                unsigned long long pk =
                    ((unsigned long long)fsort(zc[p]) << 32) | (unsigned int)fc[p];
                atomicMin(&zbuf[pixbase + (size_t)p * 4 * 256], pk);
            }
        }
    }
}

// ---------------------------------------------------------------------------
// Kernel 4: resolve. Per pixel: read winning fid, recompute w0,w1 from the
// record (same _rn sequence -> bit-identical), flow gather, bilinear sample.
// ---------------------------------------------------------------------------
__global__ __launch_bounds__(256) void resolve_kernel(
    const float* __restrict__ rast64, const float4* __restrict__ flowg,
    const unsigned long long* __restrict__ zbuf,
    const float* __restrict__ src_img, float* __restrict__ out, int B)
{
    int idx = blockIdx.x * 256 + threadIdx.x;
    if (idx >= B * HH * WW) return;
    int b = idx >> 16;
    int pix = idx & 65535;
    int pxi = pix & 255, pyi = pix >> 8;
    float px = pixc(pxi), py = pixc(pyi);

    unsigned int fid = (unsigned int)zbuf[idx];
    float fx, fy;
    if (fid != 0xFFFFFFFFu) {
        const float* r = rast64 + ((size_t)b * RASTN + fid) * 16;
        float dx = __fsub_rn(px, r[0]);
        float dy = __fsub_rn(py, r[1]);
        float w0 = __fmul_rn(__fadd_rn(__fmul_rn(r[2], dx), __fmul_rn(r[3], dy)), r[6]);
        float w1 = __fmul_rn(__fadd_rn(__fmul_rn(r[4], dx), __fmul_rn(r[5], dy)), r[6]);
        float w2 = __fsub_rn(__fsub_rn(1.0f, w0), w1);
        const float4* fg = flowg + ((size_t)b * NFACES + fid) * 2;
        float4 g0 = fg[0];
        float4 g1 = fg[1];
        fx = __fadd_rn(__fadd_rn(__fmul_rn(w0, g0.x), __fmul_rn(w1, g0.z)),
                       __fmul_rn(w2, g1.x));
        fy = __fadd_rn(__fadd_rn(__fmul_rn(w0, g0.y), __fmul_rn(w1, g0.w)),
                       __fmul_rn(w2, g1.y));
    } else {
        fx = -2.0f; fy = -2.0f;
    }

    float ix = __fmul_rn(__fsub_rn(__fmul_rn(__fadd_rn(fx, 1.0f), 256.0f), 1.0f), 0.5f);
    float iy = __fmul_rn(__fsub_rn(__fmul_rn(__fadd_rn(fy, 1.0f), 256.0f), 1.0f), 0.5f);
    ix = fminf(fmaxf(ix, 0.0f), 255.0f);
    iy = fminf(fmaxf(iy, 0.0f), 255.0f);
    float x0f = floorf(ix), y0f = floorf(iy);
    float wx = __fsub_rn(ix, x0f), wy = __fsub_rn(iy, y0f);
    int x0i = (int)x0f, y0i = (int)y0f;
    int x1i = min(x0i + 1, 255), y1i = min(y0i + 1, 255);
    float omwx = __fsub_rn(1.0f, wx), omwy = __fsub_rn(1.0f, wy);
    float wa = __fmul_rn(omwx, omwy);
    float wb = __fmul_rn(wx, omwy);
    float wc = __fmul_rn(omwx, wy);
    float wd = __fmul_rn(wx, wy);
    const float* img = src_img + (size_t)b * 3 * HH * WW;
    int o00 = y0i * WW + x0i, o01 = y0i * WW + x1i;
    int o10 = y1i * WW + x0i, o11 = y1i * WW + x1i;
    float* ob = out + (size_t)b * 3 * HH * WW + (size_t)pyi * WW + pxi;
    for (int c = 0; c < 3; ++c) {
        const float* ic = img + (size_t)c * HH * WW;
        float Ia = ic[o00], Ib = ic[o01], Ic = ic[o10], Id = ic[o11];
        float val = __fadd_rn(__fadd_rn(__fadd_rn(__fmul_rn(Ia, wa), __fmul_rn(Ib, wb)),
                                        __fmul_rn(Ic, wc)),
                              __fmul_rn(Id, wd));
        ob[(size_t)c * HH * WW] = val;
    }
}

extern "C" void kernel_launch(void* const* d_in, const int* in_sizes, int n_in,
                              void* d_out, int out_size, void* d_ws, size_t ws_size,
                              hipStream_t stream)
{
    const float* src_img   = (const float*)d_in[0];
    const float* src_cam   = (const float*)d_in[1];
    const float* src_verts = (const float*)d_in[2];
    const float* tgt_cam   = (const float*)d_in[3];
    const float* tgt_verts = (const float*)d_in[4];
    const int*   faces     = (const int*)d_in[5];
    int B = in_sizes[1] / 3;   // src_cam is [B,3]

    size_t off = 0;
    auto alloc = [&](size_t bytes) {
        size_t o = off;
        off = (off + bytes + 255) & ~(size_t)255;
        return o;
    };
    size_t rastOff = alloc((size_t)B * RASTN * 64);
    size_t bbOff   = alloc((size_t)B * NFACES * sizeof(float4));
    size_t zkOff   = alloc((size_t)B * RASTN * sizeof(unsigned int));
    size_t flowOff = alloc((size_t)B * NFACES * 2 * sizeof(float4));
    size_t zbufOff = alloc((size_t)B * HH * WW * sizeof(unsigned long long));
    size_t cntOff  = alloc((size_t)B * 256 * sizeof(int));
    size_t donOff  = alloc((size_t)B * 256 * sizeof(int));
    size_t tsOff   = alloc((size_t)B * 256 * sizeof(unsigned int));
    size_t qcOff   = alloc(sizeof(int));
    size_t quOff   = alloc((size_t)B * 256 * MAXCH * sizeof(unsigned int));
    size_t listOff = alloc((size_t)B * 256 * LISTSTRIDE * sizeof(int));
    bool binned = (off <= ws_size);

    char* ws = (char*)d_ws;
    float4* rast64 = (float4*)(ws + rastOff);
    float4* bbox   = binned ? (float4*)(ws + bbOff) : nullptr;
    unsigned int* zkeys = binned ? (unsigned int*)(ws + zkOff) : nullptr;
    float4* flowg  = (float4*)(ws + flowOff);
    unsigned long long* zbuf = (unsigned long long*)(ws + zbufOff);
    int* counts = binned ? (int*)(ws + cntOff) : nullptr;
    int* done   = binned ? (int*)(ws + donOff) : nullptr;
    unsigned int* tileSmax = binned ? (unsigned int*)(ws + tsOff) : nullptr;
    int* qcount = binned ? (int*)(ws + qcOff)  : nullptr;
    unsigned int* queue = binned ? (unsigned int*)(ws + quOff) : nullptr;
    int* lists  = binned ? (int*)(ws + listOff) : nullptr;

    int nInit = B * HH * WW;
    int nPre  = B * RASTN;
    int nMax  = nInit > nPre ? nInit : nPre;
    precompute_kernel<<<(nMax + 255) / 256, 256, 0, stream>>>(
        src_cam, src_verts, tgt_cam, tgt_verts, faces,
        rast64, bbox, zkeys, flowg, zbuf, counts, done, qcount, B);
    if (binned) {
        bin_kernel<<<dim3(256, SLABS, B), 256, 0, stream>>>(
            bbox, (const float*)rast64, lists, counts, done,
            queue, qcount, tileSmax, zbuf, B);
        raster_kernel<<<NBLK, 256, 0, stream>>>(
            (const float*)rast64, zkeys, lists, queue, qcount, tileSmax, zbuf, B);
    } else {
        raster_kernel<<<NBLK, 256, 0, stream>>>(
            (const float*)rast64, nullptr, nullptr, nullptr, nullptr, nullptr,
            zbuf, B);
    }
    resolve_kernel<<<(B * HH * WW + 255) / 256, 256, 0, stream>>>(
        (const float*)rast64, flowg, zbuf, src_img, (float*)d_out, B);
}